// Round 13
// baseline (160.121 us; speedup 1.0000x reference)
//
#include <hip/hip_runtime.h>
#include <hip/hip_bf16.h>
#include <math.h>

#define BSZ 8
#define DDIM 512
#define NND 2048
#define EE 8
#define LLH 64
#define NEDGE 524288
#define BNN 16384          // BSZ*NND
#define OCC 1536           // 3*EE*LLH
#define DQ 16384           // per-third flat d dimension

typedef __attribute__((ext_vector_type(8))) short short8;
typedef __attribute__((ext_vector_type(4))) unsigned short ushort4v;

__device__ inline unsigned short f2bf(float x) {
    __hip_bfloat16 h = __float2bfloat16(x);
    return __builtin_bit_cast(unsigned short, h);
}
__device__ inline float bf2f(unsigned short u) {
    return __uint_as_float(((unsigned int)u) << 16);
}

__device__ inline void gridbar64(int* c) {
    __syncthreads();
    if (threadIdx.x == 0) {
        __threadfence();
        atomicAdd(c, 1);
        while (atomicAdd(c, 0) < 64) __builtin_amdgcn_s_sleep(8);
        __threadfence();
    }
    __syncthreads();
}

// ---- 1. dense partials + zero hist/cbar ----
__global__ __launch_bounds__(256) void k_densep(const float* __restrict__ latent,
                                                const float* __restrict__ Wd,
                                                float* __restrict__ pdense,
                                                int* __restrict__ hist,
                                                int* __restrict__ cbar) {
    int n0 = blockIdx.x * 32, d0 = blockIdx.y * 64;
    __shared__ float lat[8][64];
    int tid = threadIdx.x;
    if (blockIdx.y == 0) hist[blockIdx.x * 256 + tid] = 0;
    if (blockIdx.x == 0 && blockIdx.y == 0 && tid < 16) cbar[tid] = 0;
    #pragma unroll
    for (int r = 0; r < 2; ++r) {
        int i = r * 256 + tid;
        lat[i >> 6][i & 63] = latent[(i >> 6) * DDIM + d0 + (i & 63)];
    }
    __syncthreads();
    int nl = tid & 31, b = tid >> 5;
    const float* wp = Wd + (size_t)d0 * NND + n0 + nl;
    float acc = 0.f;
    #pragma unroll 8
    for (int d = 0; d < 64; ++d) acc += lat[b][d] * wp[(size_t)d * NND];
    pdense[((size_t)blockIdx.y * BSZ + b) * NND + n0 + nl] = acc;
}

// ---- 2. fused: reduce partials -> conv1 -> GAT QKV projections + edge hist ----
__global__ __launch_bounds__(64) void k_gat(const float* __restrict__ pdense,
                                            const float* __restrict__ bd,
                                            const float* __restrict__ w1,
                                            const float* __restrict__ b1,
                                            const float* __restrict__ Wq, const float* __restrict__ bq,
                                            const float* __restrict__ Wk, const float* __restrict__ bk,
                                            const float* __restrict__ Wv,
                                            const int* __restrict__ ei,
                                            float* __restrict__ Qg, float* __restrict__ Kg,
                                            float* __restrict__ Vg, int* __restrict__ hist) {
    int i = blockIdx.x * 64 + threadIdx.x;
    int b = i >> 11, n = i & (NND - 1);
    float sm = 0.f, s0 = 0.f, sp = 0.f;
    #pragma unroll
    for (int ds = 0; ds < 8; ++ds) {
        const float* p = pdense + ((size_t)ds * BSZ + b) * NND + n;
        if (n > 0) sm += p[-1];
        s0 += p[0];
        if (n < NND - 1) sp += p[1];
    }
    if (n > 0) sm += bd[n - 1];
    s0 += bd[n];
    if (n < NND - 1) sp += bd[n + 1];
    float xr[EE];
    #pragma unroll
    for (int e = 0; e < EE; ++e)
        xr[e] = sm * w1[e] + s0 * w1[EE + e] + sp * w1[2 * EE + e] + b1[e];
    #pragma unroll
    for (int j = 0; j < EE; ++j) {
        float q = bq[j], k = bk[j], v = 0.f;
        #pragma unroll
        for (int c = 0; c < EE; ++c) {
            q += xr[c] * Wq[c * EE + j];
            k += xr[c] * Wk[c * EE + j];
            v += xr[c] * Wv[c * EE + j];
        }
        Qg[(size_t)i * EE + j] = (q >= 0.f) ? q : 0.2f * q;
        Kg[(size_t)i * EE + j] = (k >= 0.f) ? k : 0.2f * k;
        Vg[(size_t)i * EE + j] = v;
    }
    #pragma unroll 4
    for (int j = 0; j < 32; ++j)
        atomicAdd(hist + ei[i + j * BNN], 1);
}

// ---- 3. exclusive prefix sum over 16384 counts ----
__global__ __launch_bounds__(1024) void k_scan(const int* __restrict__ hist,
                                               int* __restrict__ offs,
                                               int* __restrict__ cnt) {
    int tid = threadIdx.x;
    int lane = tid & 63, wv = tid >> 6;
    const int4* hp = (const int4*)(hist + tid * 16);
    int4 a = hp[0], b4 = hp[1], c4 = hp[2], d4 = hp[3];
    int h[16] = {a.x, a.y, a.z, a.w, b4.x, b4.y, b4.z, b4.w,
                 c4.x, c4.y, c4.z, c4.w, d4.x, d4.y, d4.z, d4.w};
    int mysum = 0;
    #pragma unroll
    for (int i = 0; i < 16; ++i) mysum += h[i];
    int inc = mysum;
    #pragma unroll
    for (int off = 1; off < 64; off <<= 1) {
        int u = __shfl_up(inc, off, 64);
        if (lane >= off) inc += u;
    }
    __shared__ int wtot[16];
    if (lane == 63) wtot[wv] = inc;
    __syncthreads();
    if (tid < 16) {
        int t = wtot[tid];
        #pragma unroll
        for (int off = 1; off < 16; off <<= 1) {
            int u = __shfl_up(t, off, 16);
            if (tid >= off) t += u;
        }
        wtot[tid] = t;
    }
    __syncthreads();
    int run = (wv ? wtot[wv - 1] : 0) + inc - mysum;
    #pragma unroll
    for (int i = 0; i < 16; ++i) {
        offs[tid * 16 + i] = run;
        cnt[tid * 16 + i] = run;
        run += h[i];
    }
}

// ---- 4. scatter edge columns into destination buckets ----
__global__ void k_scatter(const int* __restrict__ ei, int* __restrict__ cnt,
                          int* __restrict__ ecol) {
    int e = blockIdx.x * 256 + threadIdx.x;
    if (e >= NEDGE) return;
    int r = ei[e], c = ei[NEDGE + e];
    int pos = atomicAdd(cnt + r, 1);
    ecol[pos] = c;
}

// ---- 5. per-row gather + online softmax + aggregate ----
__global__ __launch_bounds__(256) void k_gatagg(const int* __restrict__ ecol,
                                                const int* __restrict__ offs,
                                                const int* __restrict__ hist,
                                                const float* __restrict__ Qg,
                                                const float* __restrict__ Kg,
                                                const float* __restrict__ Vg,
                                                const float* __restrict__ gbias,
                                                float* __restrict__ hg) {
    int row = __builtin_amdgcn_readfirstlane(blockIdx.x * 4 + (threadIdx.x >> 6));
    int lane = threadIdx.x & 63;
    const float* Qr = Qg + (size_t)row * EE;
    float q0 = Qr[0], q1 = Qr[1], q2 = Qr[2], q3 = Qr[3];
    float q4 = Qr[4], q5 = Qr[5], q6 = Qr[6], q7 = Qr[7];
    int beg = offs[row], deg = hist[row];
    int total = deg + 1;
    float m = -INFINITY, l = 0.f;
    float acc[EE];
    #pragma unroll
    for (int j = 0; j < EE; ++j) acc[j] = 0.f;
    for (int base = 0; base < total; base += 64) {
        int idx = base + lane;
        int c = row;
        if (idx < deg) c = ecol[beg + idx];
        const float4* K4 = (const float4*)(Kg + (size_t)c * EE);
        float4 ka = K4[0], kb = K4[1];
        float s = q0*ka.x + q1*ka.y + q2*ka.z + q3*ka.w
                + q4*kb.x + q5*kb.y + q6*kb.z + q7*kb.w;
        if (idx >= total) s = -INFINITY;
        float pm = s;
        #pragma unroll
        for (int off = 32; off > 0; off >>= 1) pm = fmaxf(pm, __shfl_xor(pm, off));
        float nm = fmaxf(m, pm);
        float scale = __expf(m - nm);
        float p = (idx < total) ? __expf(s - nm) : 0.f;
        float ps = p;
        #pragma unroll
        for (int off = 32; off > 0; off >>= 1) ps += __shfl_xor(ps, off);
        l = l * scale + ps;
        const float4* V4 = (const float4*)(Vg + (size_t)c * EE);
        float4 va = V4[0], vb = V4[1];
        float pv[EE] = {p*va.x, p*va.y, p*va.z, p*va.w, p*vb.x, p*vb.y, p*vb.z, p*vb.w};
        #pragma unroll
        for (int j = 0; j < EE; ++j) {
            float t = pv[j];
            #pragma unroll
            for (int off = 32; off > 0; off >>= 1) t += __shfl_xor(t, off);
            acc[j] = acc[j] * scale + t;
        }
        m = nm;
    }
    if (lane < EE)
        hg[(size_t)row * EE + lane] = acc[lane] / l + gbias[lane];
}

// ---- 6. v-conv, 8-node chunks -> FvT[b][d][s] bf16 (688 blocks, small LDS) ----
__global__ __launch_bounds__(256) void k_convV(const float* __restrict__ hg,
                                               const float* __restrict__ qw,
                                               const float* __restrict__ qb,
                                               unsigned short* __restrict__ FvT) {
    int cx = blockIdx.x, b = blockIdx.y;
    int n0 = 682 + cx * 8;
    __shared__ float hs[10 * EE];              // rows n0-1 .. n0+8
    __shared__ unsigned short st[8 * 768];     // 12 KB per pass
    int tid = threadIdx.x;
    for (int i = tid; i < 10 * EE; i += 256) {
        int nn = n0 - 1 + (i >> 3);
        hs[i] = (nn < NND) ? hg[((size_t)b * NND + nn) * EE + (i & 7)] : 0.f;
    }
    __syncthreads();
    int dbase = n0 * 24 - DQ;
    #pragma unroll
    for (int pass = 0; pass < 2; ++pass) {
        if (pass) __syncthreads();
        float w[3][24], bias[3];
        #pragma unroll
        for (int rr = 0; rr < 3; ++rr) {
            int o = pass * 768 + rr * 256 + tid;
            bias[rr] = qb[o];
            #pragma unroll
            for (int kk = 0; kk < 24; ++kk) w[rr][kk] = qw[kk * OCC + o];
        }
        #pragma unroll
        for (int nn = 0; nn < 8; ++nn) {
            const float* hv = &hs[nn * EE];
            float a0 = bias[0], a1 = bias[1], a2 = bias[2];
            #pragma unroll
            for (int kk = 0; kk < 24; ++kk) {
                float h = hv[kk];
                a0 += h * w[0][kk]; a1 += h * w[1][kk]; a2 += h * w[2][kk];
            }
            st[nn * 768 + tid]       = f2bf(a0);
            st[nn * 768 + tid + 256] = f2bf(a1);
            st[nn * 768 + tid + 512] = f2bf(a2);
        }
        __syncthreads();
        int l0 = pass * 32;
        // transpose-write: 192 d x 8 s-groups (of 4) per pass = 1536 items
        #pragma unroll
        for (int it = 0; it < 6; ++it) {
            int idx = it * 256 + tid;
            int dl = idx >> 3, s4 = idx & 7;
            int d = dbase + dl;
            if (d < 0 || d >= DQ) continue;
            int nn = dl / 24, c = dl - nn * 24;
            const unsigned short* sb = st + nn * 768 + c;
            ushort4v v4 = { sb[(s4 * 4 + 0) * 24], sb[(s4 * 4 + 1) * 24],
                            sb[(s4 * 4 + 2) * 24], sb[(s4 * 4 + 3) * 24] };
            *(ushort4v*)(FvT + ((size_t)b * DQ + d) * 64 + l0 + s4 * 4) = v4;
        }
    }
}

// ==== 7. MSsm: 64 blocks: Mpart -> bar -> T1/S/softmax -> atT ====
__global__ __launch_bounds__(256) void k_MSsm(const float* __restrict__ hg,
                                              const float* __restrict__ qw,
                                              const float* __restrict__ qb,
                                              float* __restrict__ Mpart,
                                              float* __restrict__ atT,
                                              int* __restrict__ cbar) {
    __shared__ float smem[15400];   // 61.6 KB, aliased per phase
    int bid = blockIdx.x, tid = threadIdx.x;
    {   // ---- phase A: Mpart (sp = bid>>3, b = bid&7) ----
        int sp = bid >> 3, b = bid & 7;
        int nq0 = sp * 86;
        float* hq = smem;            // [88][8]
        float* hk = smem + 704;      // [90][8]
        for (int i = tid; i < 88 * EE; i += 256) {
            int r = nq0 - 1 + (i >> 3);
            hq[i] = (r >= 0 && r < NND) ? hg[((size_t)b * NND + r) * EE + (i & 7)] : 0.f;
        }
        for (int i = tid; i < 90 * EE; i += 256) {
            int r = nq0 + 1364 + (i >> 3);
            hk[i] = (r < NND) ? hg[((size_t)b * NND + r) * EE + (i & 7)] : 0.f;
        }
        __syncthreads();
        int cnt1 = 683 - nq0; if (cnt1 > 86) cnt1 = 86; if (cnt1 < 0) cnt1 = 0;
        int cnt2 = 682 - nq0; if (cnt2 > 86) cnt2 = 86; if (cnt2 < 0) cnt2 = 0;
        for (int idx = tid; idx < 1250; idx += 256) {
            int mm = idx / 625, p = idx - (idx / 625) * 625;
            int i = p / 25, j = p - (p / 25) * 25;
            int cnt = mm ? cnt2 : cnt1;
            int qi = i >> 3, qe = i & 7;
            int kj = (j >> 3) + mm, ke = j & 7;
            float acc = 0.f;
            if (i < 24 && j < 24) {
                for (int nl = 0; nl < cnt; ++nl)
                    acc += hq[(nl + qi) * EE + qe] * hk[(nl + kj) * EE + ke];
            } else if (i < 24) {
                for (int nl = 0; nl < cnt; ++nl) acc += hq[(nl + qi) * EE + qe];
            } else if (j < 24) {
                for (int nl = 0; nl < cnt; ++nl) acc += hk[(nl + kj) * EE + ke];
            } else {
                acc = (float)cnt;
            }
            Mpart[((size_t)(sp * 8 + b)) * 1250 + idx] = acc;
        }
    }
    gridbar64(cbar);
    {   // ---- phase B: S contraction + softmax, t = bid ----
        int t = bid;
        float* Ms = smem;            // [8][1250]
        float* As = smem + 10000;    // [25*24]
        float* T1 = smem + 10600;    // [8][600]
        for (int idx = tid; idx < 10000; idx += 256) {
            int b2 = idx / 1250, r = idx - (idx / 1250) * 1250;
            float s = 0.f;
            #pragma unroll
            for (int sp2 = 0; sp2 < 8; ++sp2)
                s += Mpart[((size_t)(sp2 * 8 + b2)) * 1250 + r];
            Ms[b2 * 1250 + r] = s;
        }
        for (int idx = tid; idx < 600; idx += 256) {
            int i = idx / 24, c = idx - (idx / 24) * 24;
            As[idx] = (i < 24) ? qw[i * OCC + t * 24 + c] : qb[t * 24 + c];
        }
        __syncthreads();
        for (int idx = tid; idx < 4800; idx += 256) {
            int b2 = idx / 600, rem = idx - (idx / 600) * 600;
            int j = rem / 24, c = rem - (rem / 24) * 24;
            int mo = (c < 16) ? 0 : 625;
            float acc = 0.f;
            #pragma unroll 5
            for (int i = 0; i < 25; ++i)
                acc += Ms[b2 * 1250 + mo + i * 25 + j] * As[i * 24 + c];
            T1[b2 * 600 + j * 24 + c] = acc;
        }
        __syncthreads();
        int s = tid & 63, bg = tid >> 6;
        float acc0 = 0.f, acc1 = 0.f;
        for (int j = 0; j < 25; ++j) {
            float Bv[24];
            const float* bp = (j < 24) ? (qw + (size_t)j * OCC + s * 24) : (qb + s * 24);
            #pragma unroll
            for (int r = 0; r < 6; ++r) {
                float4 v = *(const float4*)(bp + r * 4);
                Bv[r*4+0]=v.x; Bv[r*4+1]=v.y; Bv[r*4+2]=v.z; Bv[r*4+3]=v.w;
            }
            const float* t1a = &T1[bg * 600 + j * 24];
            const float* t1b = &T1[(bg + 4) * 600 + j * 24];
            #pragma unroll
            for (int c = 0; c < 16; ++c) {
                acc0 += t1a[c] * Bv[8 + c];
                acc1 += t1b[c] * Bv[8 + c];
            }
            #pragma unroll
            for (int c = 16; c < 24; ++c) {
                acc0 += t1a[c] * Bv[c - 16];
                acc1 += t1b[c] * Bv[c - 16];
            }
        }
        #pragma unroll
        for (int r = 0; r < 2; ++r) {
            int b2 = bg + r * 4;
            float v = r ? acc1 : acc0;
            float m = v;
            #pragma unroll
            for (int off = 32; off > 0; off >>= 1) m = fmaxf(m, __shfl_xor(m, off));
            float e = __expf(v - m);
            float sum = e;
            #pragma unroll
            for (int off = 32; off > 0; off >>= 1) sum += __shfl_xor(sum, off);
            atT[((size_t)b2 * LLH + s) * LLH + t] = e / sum;
        }
    }
}

// ---- 8. out[b][t][d] = sum_s atT[b][s][t] * v[s][d]; FvT coalesced staging ----
__global__ __launch_bounds__(256) void k_attnV(const unsigned short* __restrict__ FvT,
                                               const float* __restrict__ atT,
                                               float* __restrict__ out) {
    int b = blockIdx.y;
    int d0 = blockIdx.x * 64;
    int tid = threadIdx.x;
    __shared__ float vtf[64][65];
    #pragma unroll
    for (int r = 0; r < 2; ++r) {
        int idx = r * 256 + tid;               // 512 = 64 d x 8 groups
        int dl = idx >> 3, g = idx & 7;
        short8 v = *(const short8*)(FvT + ((size_t)b * DQ + d0 + dl) * 64 + g * 8);
        #pragma unroll
        for (int j = 0; j < 8; ++j)
            vtf[dl][g * 8 + j] = bf2f((unsigned short)v[j]);
    }
    __syncthreads();
    int lane = tid & 63;
    int t0 = __builtin_amdgcn_readfirstlane((tid >> 6) * 16);
    const float* arow = atT + (size_t)b * LLH * LLH + t0;
    float acc[16];
    #pragma unroll
    for (int tt = 0; tt < 16; ++tt) acc[tt] = 0.f;
    #pragma unroll 4
    for (int s = 0; s < LLH; ++s) {
        float vv = vtf[lane][s];
        #pragma unroll
        for (int tt = 0; tt < 16; ++tt)
            acc[tt] += arow[s * LLH + tt] * vv;   // wave-uniform -> scalar loads
    }
    float* ob = out + ((size_t)b * LLH + t0) * DQ + d0 + lane;
    #pragma unroll
    for (int tt = 0; tt < 16; ++tt) ob[(size_t)tt * DQ] = acc[tt];
}

extern "C" void kernel_launch(void* const* d_in, const int* in_sizes, int n_in,
                              void* d_out, int out_size, void* d_ws, size_t ws_size,
                              hipStream_t stream) {
    (void)in_sizes; (void)n_in; (void)out_size; (void)ws_size;
    const float* latent = (const float*)d_in[0];
    const int*   ei     = (const int*)d_in[1];
    const float* Wd     = (const float*)d_in[2];
    const float* bd     = (const float*)d_in[3];
    const float* w1     = (const float*)d_in[4];
    const float* b1     = (const float*)d_in[5];
    const float* Wq     = (const float*)d_in[6];
    const float* bq     = (const float*)d_in[7];
    const float* Wk     = (const float*)d_in[8];
    const float* bk     = (const float*)d_in[9];
    const float* Wv     = (const float*)d_in[10];
    const float* gbias  = (const float*)d_in[11];
    const float* qw     = (const float*)d_in[12];
    const float* qb     = (const float*)d_in[13];
    float* out = (float*)d_out;

    float* ws     = (float*)d_ws;
    float* pdense = ws;                          // 131072
    float* Qg     = pdense + 64 * NND;           // 131072
    float* Kg     = Qg + BNN * EE;               // 131072
    float* Vg     = Kg + BNN * EE;               // 131072
    float* hg     = Vg + BNN * EE;               // 131072
    int*   hist   = (int*)(hg + BNN * EE);       // 16384
    int*   offs   = hist + BNN;                  // 16384
    int*   cnt    = offs + BNN;                  // 16384
    int*   ecol   = cnt + BNN;                   // 524288
    int*   cbar   = ecol + NEDGE;                // 16
    float* Mp     = (float*)(cbar + 16);         // 80000
    float* atT    = Mp + 80000;                  // 32768
    unsigned short* FvT = (unsigned short*)(atT + BSZ * LLH * LLH);  // 8*16384*64 bf16

    k_densep<<<dim3(64, 8), dim3(256), 0, stream>>>(latent, Wd, pdense, hist, cbar);
    k_gat<<<dim3(256), dim3(64), 0, stream>>>(pdense, bd, w1, b1, Wq, bq, Wk, bk, Wv,
                                              ei, Qg, Kg, Vg, hist);
    k_scan<<<dim3(1), dim3(1024), 0, stream>>>(hist, offs, cnt);
    k_scatter<<<dim3(NEDGE / 256), dim3(256), 0, stream>>>(ei, cnt, ecol);
    k_gatagg<<<dim3(BNN / 4), dim3(256), 0, stream>>>(ecol, offs, hist,
                                                      Qg, Kg, Vg, gbias, hg);
    k_convV<<<dim3(86, 8), dim3(256), 0, stream>>>(hg, qw, qb, FvT);
    k_MSsm<<<dim3(64), dim3(256), 0, stream>>>(hg, qw, qb, Mp, atT, cbar);
    k_attnV<<<dim3(256, 8), dim3(256), 0, stream>>>(FvT, atT, out);
}

// Round 14
// 156.941 us; speedup vs baseline: 1.0203x; 1.0203x over previous
//
#include <hip/hip_runtime.h>
#include <hip/hip_bf16.h>
#include <math.h>

#define BSZ 8
#define DDIM 512
#define NND 2048
#define EE 8
#define LLH 64
#define NEDGE 524288
#define BNN 16384          // BSZ*NND
#define OCC 1536           // 3*EE*LLH
#define DQ 16384           // per-third flat d dimension

typedef __attribute__((ext_vector_type(8))) short short8;
typedef __attribute__((ext_vector_type(4))) unsigned short ushort4v;

__device__ inline unsigned short f2bf(float x) {
    __hip_bfloat16 h = __float2bfloat16(x);
    return __builtin_bit_cast(unsigned short, h);
}
__device__ inline float bf2f(unsigned short u) {
    return __uint_as_float(((unsigned int)u) << 16);
}

// ---- 1. dense partials + zero hist ----
__global__ __launch_bounds__(256) void k_densep(const float* __restrict__ latent,
                                                const float* __restrict__ Wd,
                                                float* __restrict__ pdense,
                                                int* __restrict__ hist) {
    int n0 = blockIdx.x * 32, d0 = blockIdx.y * 64;
    __shared__ float lat[8][64];
    int tid = threadIdx.x;
    if (blockIdx.y == 0) hist[blockIdx.x * 256 + tid] = 0;
    #pragma unroll
    for (int r = 0; r < 2; ++r) {
        int i = r * 256 + tid;
        lat[i >> 6][i & 63] = latent[(i >> 6) * DDIM + d0 + (i & 63)];
    }
    __syncthreads();
    int nl = tid & 31, b = tid >> 5;
    const float* wp = Wd + (size_t)d0 * NND + n0 + nl;
    float acc = 0.f;
    #pragma unroll 8
    for (int d = 0; d < 64; ++d) acc += lat[b][d] * wp[(size_t)d * NND];
    pdense[((size_t)blockIdx.y * BSZ + b) * NND + n0 + nl] = acc;
}

// ---- 2. fused: reduce partials -> conv1 -> GAT QKV projections + edge hist ----
__global__ __launch_bounds__(64) void k_gat(const float* __restrict__ pdense,
                                            const float* __restrict__ bd,
                                            const float* __restrict__ w1,
                                            const float* __restrict__ b1,
                                            const float* __restrict__ Wq, const float* __restrict__ bq,
                                            const float* __restrict__ Wk, const float* __restrict__ bk,
                                            const float* __restrict__ Wv,
                                            const int* __restrict__ ei,
                                            float* __restrict__ Qg, float* __restrict__ Kg,
                                            float* __restrict__ Vg, int* __restrict__ hist) {
    int i = blockIdx.x * 64 + threadIdx.x;
    int b = i >> 11, n = i & (NND - 1);
    float sm = 0.f, s0 = 0.f, sp = 0.f;
    #pragma unroll
    for (int ds = 0; ds < 8; ++ds) {
        const float* p = pdense + ((size_t)ds * BSZ + b) * NND + n;
        if (n > 0) sm += p[-1];
        s0 += p[0];
        if (n < NND - 1) sp += p[1];
    }
    if (n > 0) sm += bd[n - 1];
    s0 += bd[n];
    if (n < NND - 1) sp += bd[n + 1];
    float xr[EE];
    #pragma unroll
    for (int e = 0; e < EE; ++e)
        xr[e] = sm * w1[e] + s0 * w1[EE + e] + sp * w1[2 * EE + e] + b1[e];
    #pragma unroll
    for (int j = 0; j < EE; ++j) {
        float q = bq[j], k = bk[j], v = 0.f;
        #pragma unroll
        for (int c = 0; c < EE; ++c) {
            q += xr[c] * Wq[c * EE + j];
            k += xr[c] * Wk[c * EE + j];
            v += xr[c] * Wv[c * EE + j];
        }
        Qg[(size_t)i * EE + j] = (q >= 0.f) ? q : 0.2f * q;
        Kg[(size_t)i * EE + j] = (k >= 0.f) ? k : 0.2f * k;
        Vg[(size_t)i * EE + j] = v;
    }
    #pragma unroll 4
    for (int j = 0; j < 32; ++j)
        atomicAdd(hist + ei[i + j * BNN], 1);
}

// ---- 3. prefix sum over 16384 counts + build BsT[jc][s] table ----
__global__ __launch_bounds__(1024) void k_scan(const int* __restrict__ hist,
                                               const float* __restrict__ qw,
                                               const float* __restrict__ qb,
                                               int* __restrict__ offs,
                                               int* __restrict__ cnt,
                                               float* __restrict__ BsT) {
    int tid = threadIdx.x;
    int lane = tid & 63, wv = tid >> 6;
    const int4* hp = (const int4*)(hist + tid * 16);
    int4 a = hp[0], b4 = hp[1], c4 = hp[2], d4 = hp[3];
    int h[16] = {a.x, a.y, a.z, a.w, b4.x, b4.y, b4.z, b4.w,
                 c4.x, c4.y, c4.z, c4.w, d4.x, d4.y, d4.z, d4.w};
    int mysum = 0;
    #pragma unroll
    for (int i = 0; i < 16; ++i) mysum += h[i];
    int inc = mysum;
    #pragma unroll
    for (int off = 1; off < 64; off <<= 1) {
        int u = __shfl_up(inc, off, 64);
        if (lane >= off) inc += u;
    }
    __shared__ int wtot[16];
    if (lane == 63) wtot[wv] = inc;
    __syncthreads();
    if (tid < 16) {
        int t = wtot[tid];
        #pragma unroll
        for (int off = 1; off < 16; off <<= 1) {
            int u = __shfl_up(t, off, 16);
            if (tid >= off) t += u;
        }
        wtot[tid] = t;
    }
    __syncthreads();
    int run = (wv ? wtot[wv - 1] : 0) + inc - mysum;
    #pragma unroll
    for (int i = 0; i < 16; ++i) {
        offs[tid * 16 + i] = run;
        cnt[tid * 16 + i] = run;
        run += h[i];
    }
    // BsT[jc*64+s] = B[j][s*24+sigma(c)], j=jc/24, c=jc%24, sigma(c)=c<16?c+8:c-16
    for (int idx = tid; idx < 38400; idx += 1024) {
        int jc = idx >> 6, s = idx & 63;
        int j = jc / 24, c = jc - j * 24;
        int sc = (c < 16) ? c + 8 : c - 16;
        float v = (j < 24) ? qw[(size_t)j * OCC + s * 24 + sc] : qb[s * 24 + sc];
        BsT[idx] = v;
    }
}

// ---- 4. scatter edge columns into destination buckets ----
__global__ void k_scatter(const int* __restrict__ ei, int* __restrict__ cnt,
                          int* __restrict__ ecol) {
    int e = blockIdx.x * 256 + threadIdx.x;
    if (e >= NEDGE) return;
    int r = ei[e], c = ei[NEDGE + e];
    int pos = atomicAdd(cnt + r, 1);
    ecol[pos] = c;
}

// ---- 5. per-row gather + online softmax + aggregate ----
__global__ __launch_bounds__(256) void k_gatagg(const int* __restrict__ ecol,
                                                const int* __restrict__ offs,
                                                const int* __restrict__ hist,
                                                const float* __restrict__ Qg,
                                                const float* __restrict__ Kg,
                                                const float* __restrict__ Vg,
                                                const float* __restrict__ gbias,
                                                float* __restrict__ hg) {
    int row = __builtin_amdgcn_readfirstlane(blockIdx.x * 4 + (threadIdx.x >> 6));
    int lane = threadIdx.x & 63;
    const float* Qr = Qg + (size_t)row * EE;
    float q0 = Qr[0], q1 = Qr[1], q2 = Qr[2], q3 = Qr[3];
    float q4 = Qr[4], q5 = Qr[5], q6 = Qr[6], q7 = Qr[7];
    int beg = offs[row], deg = hist[row];
    int total = deg + 1;
    float m = -INFINITY, l = 0.f;
    float acc[EE];
    #pragma unroll
    for (int j = 0; j < EE; ++j) acc[j] = 0.f;
    for (int base = 0; base < total; base += 64) {
        int idx = base + lane;
        int c = row;
        if (idx < deg) c = ecol[beg + idx];
        const float4* K4 = (const float4*)(Kg + (size_t)c * EE);
        float4 ka = K4[0], kb = K4[1];
        float s = q0*ka.x + q1*ka.y + q2*ka.z + q3*ka.w
                + q4*kb.x + q5*kb.y + q6*kb.z + q7*kb.w;
        if (idx >= total) s = -INFINITY;
        float pm = s;
        #pragma unroll
        for (int off = 32; off > 0; off >>= 1) pm = fmaxf(pm, __shfl_xor(pm, off));
        float nm = fmaxf(m, pm);
        float scale = __expf(m - nm);
        float p = (idx < total) ? __expf(s - nm) : 0.f;
        float ps = p;
        #pragma unroll
        for (int off = 32; off > 0; off >>= 1) ps += __shfl_xor(ps, off);
        l = l * scale + ps;
        const float4* V4 = (const float4*)(Vg + (size_t)c * EE);
        float4 va = V4[0], vb = V4[1];
        float pv[EE] = {p*va.x, p*va.y, p*va.z, p*va.w, p*vb.x, p*vb.y, p*vb.z, p*vb.w};
        #pragma unroll
        for (int j = 0; j < EE; ++j) {
            float t = pv[j];
            #pragma unroll
            for (int off = 32; off > 0; off >>= 1) t += __shfl_xor(t, off);
            acc[j] = acc[j] * scale + t;
        }
        m = nm;
    }
    if (lane < EE)
        hg[(size_t)row * EE + lane] = acc[lane] / l + gbias[lane];
}

// ---- 6. v-conv (8-node chunks) -> FvT[b][d][s]  ||  Mpart (bx>=86) ----
// grid (94, 8)
__global__ __launch_bounds__(256) void k_convV(const float* __restrict__ hg,
                                               const float* __restrict__ qw,
                                               const float* __restrict__ qb,
                                               unsigned short* __restrict__ FvT,
                                               float* __restrict__ Mpart) {
    int bx = blockIdx.x, b = blockIdx.y, tid = threadIdx.x;
    if (bx < 86) {
        int n0 = 682 + bx * 8;
        __shared__ float hs[10 * EE];              // rows n0-1 .. n0+8
        __shared__ unsigned short st[8 * 768];     // 12 KB
        for (int i = tid; i < 10 * EE; i += 256) {
            int nn = n0 - 1 + (i >> 3);
            hs[i] = (nn < NND) ? hg[((size_t)b * NND + nn) * EE + (i & 7)] : 0.f;
        }
        __syncthreads();
        int dbase = n0 * 24 - DQ;
        #pragma unroll
        for (int pass = 0; pass < 2; ++pass) {
            if (pass) __syncthreads();
            float w[3][24], bias[3];
            #pragma unroll
            for (int rr = 0; rr < 3; ++rr) {
                int o = pass * 768 + rr * 256 + tid;
                bias[rr] = qb[o];
                #pragma unroll
                for (int kk = 0; kk < 24; ++kk) w[rr][kk] = qw[kk * OCC + o];
            }
            #pragma unroll
            for (int nn = 0; nn < 8; ++nn) {
                const float* hv = &hs[nn * EE];
                float a0 = bias[0], a1 = bias[1], a2 = bias[2];
                #pragma unroll
                for (int kk = 0; kk < 24; ++kk) {
                    float h = hv[kk];
                    a0 += h * w[0][kk]; a1 += h * w[1][kk]; a2 += h * w[2][kk];
                }
                st[nn * 768 + tid]       = f2bf(a0);
                st[nn * 768 + tid + 256] = f2bf(a1);
                st[nn * 768 + tid + 512] = f2bf(a2);
            }
            __syncthreads();
            int l0 = pass * 32;
            #pragma unroll
            for (int it = 0; it < 6; ++it) {
                int idx = it * 256 + tid;
                int dl = idx >> 3, s4 = idx & 7;
                int d = dbase + dl;
                if (d < 0 || d >= DQ) continue;
                int nn = dl / 24, c = dl - nn * 24;
                const unsigned short* sb = st + nn * 768 + c;
                ushort4v v4 = { sb[(s4 * 4 + 0) * 24], sb[(s4 * 4 + 1) * 24],
                                sb[(s4 * 4 + 2) * 24], sb[(s4 * 4 + 3) * 24] };
                *(ushort4v*)(FvT + ((size_t)b * DQ + d) * 64 + l0 + s4 * 4) = v4;
            }
        }
    } else {
        // Mpart role: sp = bx-86
        int sp = bx - 86;
        int nq0 = sp * 86;
        __shared__ float hq[88 * EE];
        __shared__ float hk[90 * EE];
        for (int i = tid; i < 88 * EE; i += 256) {
            int r = nq0 - 1 + (i >> 3);
            hq[i] = (r >= 0 && r < NND) ? hg[((size_t)b * NND + r) * EE + (i & 7)] : 0.f;
        }
        for (int i = tid; i < 90 * EE; i += 256) {
            int r = nq0 + 1364 + (i >> 3);
            hk[i] = (r < NND) ? hg[((size_t)b * NND + r) * EE + (i & 7)] : 0.f;
        }
        __syncthreads();
        int cnt1 = 683 - nq0; if (cnt1 > 86) cnt1 = 86; if (cnt1 < 0) cnt1 = 0;
        int cnt2 = 682 - nq0; if (cnt2 > 86) cnt2 = 86; if (cnt2 < 0) cnt2 = 0;
        for (int idx = tid; idx < 1250; idx += 256) {
            int mm = idx / 625, p = idx - (idx / 625) * 625;
            int i = p / 25, j = p - (p / 25) * 25;
            int cnt = mm ? cnt2 : cnt1;
            int qi = i >> 3, qe = i & 7;
            int kj = (j >> 3) + mm, ke = j & 7;
            float acc = 0.f;
            if (i < 24 && j < 24) {
                for (int nl = 0; nl < cnt; ++nl)
                    acc += hq[(nl + qi) * EE + qe] * hk[(nl + kj) * EE + ke];
            } else if (i < 24) {
                for (int nl = 0; nl < cnt; ++nl) acc += hq[(nl + qi) * EE + qe];
            } else if (j < 24) {
                for (int nl = 0; nl < cnt; ++nl) acc += hk[(nl + kj) * EE + ke];
            } else {
                acc = (float)cnt;
            }
            Mpart[((size_t)(sp * 8 + b)) * 1250 + idx] = acc;
        }
    }
}

// ==== 7. S contraction + softmax, grid (64 t, 8 b) x 256 thr ====
// T1[j*24+c] = sum_i M[m(c)][i][j]*A[i][t*24+c]; S[s] = sum_jc T1[jc]*BsT[jc][s]
__global__ __launch_bounds__(256) void k_Ssm(const float* __restrict__ qw,
                                             const float* __restrict__ qb,
                                             const float* __restrict__ Mpart,
                                             const float* __restrict__ BsT,
                                             float* __restrict__ atT) {
    int t = blockIdx.x, b = blockIdx.y, tid = threadIdx.x;
    __shared__ float Ms[1250];
    __shared__ float As[600];
    __shared__ float T1[600];
    __shared__ float part[4][64];
    for (int idx = tid; idx < 1250; idx += 256) {
        float s = 0.f;
        #pragma unroll
        for (int sp = 0; sp < 8; ++sp)
            s += Mpart[((size_t)(sp * 8 + b)) * 1250 + idx];
        Ms[idx] = s;
    }
    for (int idx = tid; idx < 600; idx += 256) {
        int i = idx / 24, c = idx - (idx / 24) * 24;
        As[idx] = (i < 24) ? qw[(size_t)i * OCC + t * 24 + c] : qb[t * 24 + c];
    }
    __syncthreads();
    for (int idx = tid; idx < 600; idx += 256) {
        int j = idx / 24, c = idx - (idx / 24) * 24;
        int mo = (c < 16) ? 0 : 625;
        float acc = 0.f;
        #pragma unroll 5
        for (int i = 0; i < 25; ++i)
            acc += Ms[mo + i * 25 + j] * As[i * 24 + c];
        T1[idx] = acc;
    }
    __syncthreads();
    int s = tid & 63, g = tid >> 6;
    float acc = 0.f;
    const float* bp = BsT + (size_t)(g * 150) * 64 + s;
    #pragma unroll 10
    for (int u = 0; u < 150; ++u)
        acc += T1[g * 150 + u] * bp[(size_t)u * 64];
    part[g][s] = acc;
    __syncthreads();
    if (tid < 64) {
        float v = part[0][s] + part[1][s] + part[2][s] + part[3][s];
        float m = v;
        #pragma unroll
        for (int off = 32; off > 0; off >>= 1) m = fmaxf(m, __shfl_xor(m, off));
        float e = __expf(v - m);
        float sum = e;
        #pragma unroll
        for (int off = 32; off > 0; off >>= 1) sum += __shfl_xor(sum, off);
        atT[((size_t)b * LLH + s) * LLH + t] = e / sum;
    }
}

// ---- 8. out[b][t][d] = sum_s atT[b][s][t] * v[s][d]; FvT coalesced staging ----
__global__ __launch_bounds__(256) void k_attnV(const unsigned short* __restrict__ FvT,
                                               const float* __restrict__ atT,
                                               float* __restrict__ out) {
    int b = blockIdx.y;
    int d0 = blockIdx.x * 64;
    int tid = threadIdx.x;
    __shared__ float vtf[64][65];
    #pragma unroll
    for (int r = 0; r < 2; ++r) {
        int idx = r * 256 + tid;               // 512 = 64 d x 8 groups
        int dl = idx >> 3, g = idx & 7;
        short8 v = *(const short8*)(FvT + ((size_t)b * DQ + d0 + dl) * 64 + g * 8);
        #pragma unroll
        for (int j = 0; j < 8; ++j)
            vtf[dl][g * 8 + j] = bf2f((unsigned short)v[j]);
    }
    __syncthreads();
    int lane = tid & 63;
    int t0 = __builtin_amdgcn_readfirstlane((tid >> 6) * 16);
    const float* arow = atT + (size_t)b * LLH * LLH + t0;
    float acc[16];
    #pragma unroll
    for (int tt = 0; tt < 16; ++tt) acc[tt] = 0.f;
    #pragma unroll 4
    for (int s = 0; s < LLH; ++s) {
        float vv = vtf[lane][s];
        #pragma unroll
        for (int tt = 0; tt < 16; ++tt)
            acc[tt] += arow[s * LLH + tt] * vv;   // wave-uniform -> scalar loads
    }
    float* ob = out + ((size_t)b * LLH + t0) * DQ + d0 + lane;
    #pragma unroll
    for (int tt = 0; tt < 16; ++tt) ob[(size_t)tt * DQ] = acc[tt];
}

extern "C" void kernel_launch(void* const* d_in, const int* in_sizes, int n_in,
                              void* d_out, int out_size, void* d_ws, size_t ws_size,
                              hipStream_t stream) {
    (void)in_sizes; (void)n_in; (void)out_size; (void)ws_size;
    const float* latent = (const float*)d_in[0];
    const int*   ei     = (const int*)d_in[1];
    const float* Wd     = (const float*)d_in[2];
    const float* bd     = (const float*)d_in[3];
    const float* w1     = (const float*)d_in[4];
    const float* b1     = (const float*)d_in[5];
    const float* Wq     = (const float*)d_in[6];
    const float* bq     = (const float*)d_in[7];
    const float* Wk     = (const float*)d_in[8];
    const float* bk     = (const float*)d_in[9];
    const float* Wv     = (const float*)d_in[10];
    const float* gbias  = (const float*)d_in[11];
    const float* qw     = (const float*)d_in[12];
    const float* qb     = (const float*)d_in[13];
    float* out = (float*)d_out;

    float* ws     = (float*)d_ws;
    float* pdense = ws;                          // 131072
    float* Qg     = pdense + 64 * NND;           // 131072
    float* Kg     = Qg + BNN * EE;               // 131072
    float* Vg     = Kg + BNN * EE;               // 131072
    float* hg     = Vg + BNN * EE;               // 131072
    int*   hist   = (int*)(hg + BNN * EE);       // 16384
    int*   offs   = hist + BNN;                  // 16384
    int*   cnt    = offs + BNN;                  // 16384
    int*   ecol   = cnt + BNN;                   // 524288
    float* Mp     = (float*)(ecol + NEDGE);      // 80000
    float* BsT    = Mp + 80000;                  // 38400
    float* atT    = BsT + 38400;                 // 32768
    unsigned short* FvT = (unsigned short*)(atT + BSZ * LLH * LLH);  // 8*16384*64 bf16

    k_densep<<<dim3(64, 8), dim3(256), 0, stream>>>(latent, Wd, pdense, hist);
    k_gat<<<dim3(256), dim3(64), 0, stream>>>(pdense, bd, w1, b1, Wq, bq, Wk, bk, Wv,
                                              ei, Qg, Kg, Vg, hist);
    k_scan<<<dim3(1), dim3(1024), 0, stream>>>(hist, qw, qb, offs, cnt, BsT);
    k_scatter<<<dim3(NEDGE / 256), dim3(256), 0, stream>>>(ei, cnt, ecol);
    k_gatagg<<<dim3(BNN / 4), dim3(256), 0, stream>>>(ecol, offs, hist,
                                                      Qg, Kg, Vg, gbias, hg);
    k_convV<<<dim3(94, 8), dim3(256), 0, stream>>>(hg, qw, qb, FvT, Mp);
    k_Ssm<<<dim3(64, 8), dim3(256), 0, stream>>>(qw, qb, Mp, BsT, atT);
    k_attnV<<<dim3(256, 8), dim3(256), 0, stream>>>(FvT, atT, out);
}

// Round 15
// 137.058 us; speedup vs baseline: 1.1683x; 1.1451x over previous
//
#include <hip/hip_runtime.h>
#include <hip/hip_bf16.h>
#include <math.h>

#define BSZ 8
#define DDIM 512
#define NND 2048
#define EE 8
#define LLH 64
#define NEDGE 524288
#define BNN 16384          // BSZ*NND
#define OCC 1536           // 3*EE*LLH
#define DQ 16384           // per-third flat d dimension

typedef __attribute__((ext_vector_type(8))) short short8;
typedef __attribute__((ext_vector_type(4))) unsigned short ushort4v;

__device__ inline unsigned short f2bf(float x) {
    __hip_bfloat16 h = __float2bfloat16(x);
    return __builtin_bit_cast(unsigned short, h);
}
__device__ inline float bf2f(unsigned short u) {
    return __uint_as_float(((unsigned int)u) << 16);
}

// ---- 1. dense partials + zero hist + build BsT (by==1 slice) ----
__global__ __launch_bounds__(256) void k_densep(const float* __restrict__ latent,
                                                const float* __restrict__ Wd,
                                                const float* __restrict__ qw,
                                                const float* __restrict__ qb,
                                                float* __restrict__ pdense,
                                                int* __restrict__ hist,
                                                float* __restrict__ BsT) {
    int n0 = blockIdx.x * 32, d0 = blockIdx.y * 64;
    __shared__ float lat[8][64];
    int tid = threadIdx.x;
    if (blockIdx.y == 0) hist[blockIdx.x * 256 + tid] = 0;
    if (blockIdx.y == 1) {
        // BsT[jc*64+s] = B[j][s*24+sigma(c)], sigma(c)=c<16?c+8:c-16
        for (int idx = blockIdx.x * 256 + tid; idx < 38400; idx += 16384) {
            int jc = idx >> 6, s = idx & 63;
            int j = jc / 24, c = jc - j * 24;
            int sc = (c < 16) ? c + 8 : c - 16;
            BsT[idx] = (j < 24) ? qw[(size_t)j * OCC + s * 24 + sc] : qb[s * 24 + sc];
        }
    }
    #pragma unroll
    for (int r = 0; r < 2; ++r) {
        int i = r * 256 + tid;
        lat[i >> 6][i & 63] = latent[(i >> 6) * DDIM + d0 + (i & 63)];
    }
    __syncthreads();
    int nl = tid & 31, b = tid >> 5;
    const float* wp = Wd + (size_t)d0 * NND + n0 + nl;
    float acc = 0.f;
    #pragma unroll 8
    for (int d = 0; d < 64; ++d) acc += lat[b][d] * wp[(size_t)d * NND];
    pdense[((size_t)blockIdx.y * BSZ + b) * NND + n0 + nl] = acc;
}

// ---- 2. fused: reduce partials -> conv1 -> GAT QKV projections + edge hist ----
__global__ __launch_bounds__(64) void k_gat(const float* __restrict__ pdense,
                                            const float* __restrict__ bd,
                                            const float* __restrict__ w1,
                                            const float* __restrict__ b1,
                                            const float* __restrict__ Wq, const float* __restrict__ bq,
                                            const float* __restrict__ Wk, const float* __restrict__ bk,
                                            const float* __restrict__ Wv,
                                            const int* __restrict__ ei,
                                            float* __restrict__ Qg, float* __restrict__ Kg,
                                            float* __restrict__ Vg, int* __restrict__ hist) {
    int i = blockIdx.x * 64 + threadIdx.x;
    int b = i >> 11, n = i & (NND - 1);
    float sm = 0.f, s0 = 0.f, sp = 0.f;
    #pragma unroll
    for (int ds = 0; ds < 8; ++ds) {
        const float* p = pdense + ((size_t)ds * BSZ + b) * NND + n;
        if (n > 0) sm += p[-1];
        s0 += p[0];
        if (n < NND - 1) sp += p[1];
    }
    if (n > 0) sm += bd[n - 1];
    s0 += bd[n];
    if (n < NND - 1) sp += bd[n + 1];
    float xr[EE];
    #pragma unroll
    for (int e = 0; e < EE; ++e)
        xr[e] = sm * w1[e] + s0 * w1[EE + e] + sp * w1[2 * EE + e] + b1[e];
    #pragma unroll
    for (int j = 0; j < EE; ++j) {
        float q = bq[j], k = bk[j], v = 0.f;
        #pragma unroll
        for (int c = 0; c < EE; ++c) {
            q += xr[c] * Wq[c * EE + j];
            k += xr[c] * Wk[c * EE + j];
            v += xr[c] * Wv[c * EE + j];
        }
        Qg[(size_t)i * EE + j] = (q >= 0.f) ? q : 0.2f * q;
        Kg[(size_t)i * EE + j] = (k >= 0.f) ? k : 0.2f * k;
        Vg[(size_t)i * EE + j] = v;
    }
    #pragma unroll 4
    for (int j = 0; j < 32; ++j)
        atomicAdd(hist + ei[i + j * BNN], 1);
}

// ---- 3. exclusive prefix sum over 16384 counts ----
__global__ __launch_bounds__(1024) void k_scan(const int* __restrict__ hist,
                                               int* __restrict__ offs,
                                               int* __restrict__ cnt) {
    int tid = threadIdx.x;
    int lane = tid & 63, wv = tid >> 6;
    const int4* hp = (const int4*)(hist + tid * 16);
    int4 a = hp[0], b4 = hp[1], c4 = hp[2], d4 = hp[3];
    int h[16] = {a.x, a.y, a.z, a.w, b4.x, b4.y, b4.z, b4.w,
                 c4.x, c4.y, c4.z, c4.w, d4.x, d4.y, d4.z, d4.w};
    int mysum = 0;
    #pragma unroll
    for (int i = 0; i < 16; ++i) mysum += h[i];
    int inc = mysum;
    #pragma unroll
    for (int off = 1; off < 64; off <<= 1) {
        int u = __shfl_up(inc, off, 64);
        if (lane >= off) inc += u;
    }
    __shared__ int wtot[16];
    if (lane == 63) wtot[wv] = inc;
    __syncthreads();
    if (tid < 16) {
        int t = wtot[tid];
        #pragma unroll
        for (int off = 1; off < 16; off <<= 1) {
            int u = __shfl_up(t, off, 16);
            if (tid >= off) t += u;
        }
        wtot[tid] = t;
    }
    __syncthreads();
    int run = (wv ? wtot[wv - 1] : 0) + inc - mysum;
    #pragma unroll
    for (int i = 0; i < 16; ++i) {
        offs[tid * 16 + i] = run;
        cnt[tid * 16 + i] = run;
        run += h[i];
    }
}

// ---- 4. scatter edge columns into destination buckets ----
__global__ void k_scatter(const int* __restrict__ ei, int* __restrict__ cnt,
                          int* __restrict__ ecol) {
    int e = blockIdx.x * 256 + threadIdx.x;
    if (e >= NEDGE) return;
    int r = ei[e], c = ei[NEDGE + e];
    int pos = atomicAdd(cnt + r, 1);
    ecol[pos] = c;
}

// ---- 5. per-row gather + online softmax + aggregate ----
__global__ __launch_bounds__(256) void k_gatagg(const int* __restrict__ ecol,
                                                const int* __restrict__ offs,
                                                const int* __restrict__ hist,
                                                const float* __restrict__ Qg,
                                                const float* __restrict__ Kg,
                                                const float* __restrict__ Vg,
                                                const float* __restrict__ gbias,
                                                float* __restrict__ hg) {
    int row = __builtin_amdgcn_readfirstlane(blockIdx.x * 4 + (threadIdx.x >> 6));
    int lane = threadIdx.x & 63;
    const float* Qr = Qg + (size_t)row * EE;
    float q0 = Qr[0], q1 = Qr[1], q2 = Qr[2], q3 = Qr[3];
    float q4 = Qr[4], q5 = Qr[5], q6 = Qr[6], q7 = Qr[7];
    int beg = offs[row], deg = hist[row];
    int total = deg + 1;
    float m = -INFINITY, l = 0.f;
    float acc[EE];
    #pragma unroll
    for (int j = 0; j < EE; ++j) acc[j] = 0.f;
    for (int base = 0; base < total; base += 64) {
        int idx = base + lane;
        int c = row;
        if (idx < deg) c = ecol[beg + idx];
        const float4* K4 = (const float4*)(Kg + (size_t)c * EE);
        float4 ka = K4[0], kb = K4[1];
        float s = q0*ka.x + q1*ka.y + q2*ka.z + q3*ka.w
                + q4*kb.x + q5*kb.y + q6*kb.z + q7*kb.w;
        if (idx >= total) s = -INFINITY;
        float pm = s;
        #pragma unroll
        for (int off = 32; off > 0; off >>= 1) pm = fmaxf(pm, __shfl_xor(pm, off));
        float nm = fmaxf(m, pm);
        float scale = __expf(m - nm);
        float p = (idx < total) ? __expf(s - nm) : 0.f;
        float ps = p;
        #pragma unroll
        for (int off = 32; off > 0; off >>= 1) ps += __shfl_xor(ps, off);
        l = l * scale + ps;
        const float4* V4 = (const float4*)(Vg + (size_t)c * EE);
        float4 va = V4[0], vb = V4[1];
        float pv[EE] = {p*va.x, p*va.y, p*va.z, p*va.w, p*vb.x, p*vb.y, p*vb.z, p*vb.w};
        #pragma unroll
        for (int j = 0; j < EE; ++j) {
            float t = pv[j];
            #pragma unroll
            for (int off = 32; off > 0; off >>= 1) t += __shfl_xor(t, off);
            acc[j] = acc[j] * scale + t;
        }
        m = nm;
    }
    if (lane < EE)
        hg[(size_t)row * EE + lane] = acc[lane] / l + gbias[lane];
}

// ---- 6. v-conv (8-node chunks) -> FvT[b][d][s]  ||  Mpart (bx>=86) ----
__global__ __launch_bounds__(256) void k_convV(const float* __restrict__ hg,
                                               const float* __restrict__ qw,
                                               const float* __restrict__ qb,
                                               unsigned short* __restrict__ FvT,
                                               float* __restrict__ Mpart) {
    int bx = blockIdx.x, b = blockIdx.y, tid = threadIdx.x;
    if (bx < 86) {
        int n0 = 682 + bx * 8;
        __shared__ float hs[10 * EE];
        __shared__ unsigned short st[8 * 768];
        for (int i = tid; i < 10 * EE; i += 256) {
            int nn = n0 - 1 + (i >> 3);
            hs[i] = (nn < NND) ? hg[((size_t)b * NND + nn) * EE + (i & 7)] : 0.f;
        }
        __syncthreads();
        int dbase = n0 * 24 - DQ;
        #pragma unroll
        for (int pass = 0; pass < 2; ++pass) {
            if (pass) __syncthreads();
            float w[3][24], bias[3];
            #pragma unroll
            for (int rr = 0; rr < 3; ++rr) {
                int o = pass * 768 + rr * 256 + tid;
                bias[rr] = qb[o];
                #pragma unroll
                for (int kk = 0; kk < 24; ++kk) w[rr][kk] = qw[kk * OCC + o];
            }
            #pragma unroll
            for (int nn = 0; nn < 8; ++nn) {
                const float* hv = &hs[nn * EE];
                float a0 = bias[0], a1 = bias[1], a2 = bias[2];
                #pragma unroll
                for (int kk = 0; kk < 24; ++kk) {
                    float h = hv[kk];
                    a0 += h * w[0][kk]; a1 += h * w[1][kk]; a2 += h * w[2][kk];
                }
                st[nn * 768 + tid]       = f2bf(a0);
                st[nn * 768 + tid + 256] = f2bf(a1);
                st[nn * 768 + tid + 512] = f2bf(a2);
            }
            __syncthreads();
            int l0 = pass * 32;
            #pragma unroll
            for (int it = 0; it < 6; ++it) {
                int idx = it * 256 + tid;
                int dl = idx >> 3, s4 = idx & 7;
                int d = dbase + dl;
                if (d < 0 || d >= DQ) continue;
                int nn = dl / 24, c = dl - nn * 24;
                const unsigned short* sb = st + nn * 768 + c;
                ushort4v v4 = { sb[(s4 * 4 + 0) * 24], sb[(s4 * 4 + 1) * 24],
                                sb[(s4 * 4 + 2) * 24], sb[(s4 * 4 + 3) * 24] };
                *(ushort4v*)(FvT + ((size_t)b * DQ + d) * 64 + l0 + s4 * 4) = v4;
            }
        }
    } else {
        int sp = bx - 86;
        int nq0 = sp * 86;
        __shared__ float hq[88 * EE];
        __shared__ float hk[90 * EE];
        for (int i = tid; i < 88 * EE; i += 256) {
            int r = nq0 - 1 + (i >> 3);
            hq[i] = (r >= 0 && r < NND) ? hg[((size_t)b * NND + r) * EE + (i & 7)] : 0.f;
        }
        for (int i = tid; i < 90 * EE; i += 256) {
            int r = nq0 + 1364 + (i >> 3);
            hk[i] = (r < NND) ? hg[((size_t)b * NND + r) * EE + (i & 7)] : 0.f;
        }
        __syncthreads();
        int cnt1 = 683 - nq0; if (cnt1 > 86) cnt1 = 86; if (cnt1 < 0) cnt1 = 0;
        int cnt2 = 682 - nq0; if (cnt2 > 86) cnt2 = 86; if (cnt2 < 0) cnt2 = 0;
        for (int idx = tid; idx < 1250; idx += 256) {
            int mm = idx / 625, p = idx - (idx / 625) * 625;
            int i = p / 25, j = p - (p / 25) * 25;
            int cnt = mm ? cnt2 : cnt1;
            int qi = i >> 3, qe = i & 7;
            int kj = (j >> 3) + mm, ke = j & 7;
            float acc = 0.f;
            if (i < 24 && j < 24) {
                for (int nl = 0; nl < cnt; ++nl)
                    acc += hq[(nl + qi) * EE + qe] * hk[(nl + kj) * EE + ke];
            } else if (i < 24) {
                for (int nl = 0; nl < cnt; ++nl) acc += hq[(nl + qi) * EE + qe];
            } else if (j < 24) {
                for (int nl = 0; nl < cnt; ++nl) acc += hk[(nl + kj) * EE + ke];
            } else {
                acc = (float)cnt;
            }
            Mpart[((size_t)(sp * 8 + b)) * 1250 + idx] = acc;
        }
    }
}

// ---- 7. S contraction + softmax, grid (64 t, 8 b) x 256 thr ----
__global__ __launch_bounds__(256) void k_Ssm(const float* __restrict__ qw,
                                             const float* __restrict__ qb,
                                             const float* __restrict__ Mpart,
                                             const float* __restrict__ BsT,
                                             float* __restrict__ atT) {
    int t = blockIdx.x, b = blockIdx.y, tid = threadIdx.x;
    __shared__ float Ms[1250];
    __shared__ float As[600];
    __shared__ float T1[600];
    __shared__ float part[4][64];
    for (int idx = tid; idx < 1250; idx += 256) {
        float s = 0.f;
        #pragma unroll
        for (int sp = 0; sp < 8; ++sp)
            s += Mpart[((size_t)(sp * 8 + b)) * 1250 + idx];
        Ms[idx] = s;
    }
    for (int idx = tid; idx < 600; idx += 256) {
        int i = idx / 24, c = idx - (idx / 24) * 24;
        As[idx] = (i < 24) ? qw[(size_t)i * OCC + t * 24 + c] : qb[t * 24 + c];
    }
    __syncthreads();
    for (int idx = tid; idx < 600; idx += 256) {
        int j = idx / 24, c = idx - (idx / 24) * 24;
        int mo = (c < 16) ? 0 : 625;
        float acc = 0.f;
        #pragma unroll 5
        for (int i = 0; i < 25; ++i)
            acc += Ms[mo + i * 25 + j] * As[i * 24 + c];
        T1[idx] = acc;
    }
    __syncthreads();
    int s = tid & 63, g = tid >> 6;
    float acc = 0.f;
    const float* bp = BsT + (size_t)(g * 150) * 64 + s;
    #pragma unroll 10
    for (int u = 0; u < 150; ++u)
        acc += T1[g * 150 + u] * bp[(size_t)u * 64];
    part[g][s] = acc;
    __syncthreads();
    if (tid < 64) {
        float v = part[0][s] + part[1][s] + part[2][s] + part[3][s];
        float m = v;
        #pragma unroll
        for (int off = 32; off > 0; off >>= 1) m = fmaxf(m, __shfl_xor(m, off));
        float e = __expf(v - m);
        float sum = e;
        #pragma unroll
        for (int off = 32; off > 0; off >>= 1) sum += __shfl_xor(sum, off);
        atT[((size_t)b * LLH + s) * LLH + t] = e / sum;
    }
}

// ---- 8. out[b][t][d] = sum_s atT[b][s][t] * v[s][d]; FvT coalesced staging ----
__global__ __launch_bounds__(256) void k_attnV(const unsigned short* __restrict__ FvT,
                                               const float* __restrict__ atT,
                                               float* __restrict__ out) {
    int b = blockIdx.y;
    int d0 = blockIdx.x * 64;
    int tid = threadIdx.x;
    __shared__ float vtf[64][65];
    #pragma unroll
    for (int r = 0; r < 2; ++r) {
        int idx = r * 256 + tid;
        int dl = idx >> 3, g = idx & 7;
        short8 v = *(const short8*)(FvT + ((size_t)b * DQ + d0 + dl) * 64 + g * 8);
        #pragma unroll
        for (int j = 0; j < 8; ++j)
            vtf[dl][g * 8 + j] = bf2f((unsigned short)v[j]);
    }
    __syncthreads();
    int lane = tid & 63;
    int t0 = __builtin_amdgcn_readfirstlane((tid >> 6) * 16);
    const float* arow = atT + (size_t)b * LLH * LLH + t0;
    float acc[16];
    #pragma unroll
    for (int tt = 0; tt < 16; ++tt) acc[tt] = 0.f;
    #pragma unroll 4
    for (int s = 0; s < LLH; ++s) {
        float vv = vtf[lane][s];
        #pragma unroll
        for (int tt = 0; tt < 16; ++tt)
            acc[tt] += arow[s * LLH + tt] * vv;
    }
    float* ob = out + ((size_t)b * LLH + t0) * DQ + d0 + lane;
    #pragma unroll
    for (int tt = 0; tt < 16; ++tt) ob[(size_t)tt * DQ] = acc[tt];
}

extern "C" void kernel_launch(void* const* d_in, const int* in_sizes, int n_in,
                              void* d_out, int out_size, void* d_ws, size_t ws_size,
                              hipStream_t stream) {
    (void)in_sizes; (void)n_in; (void)out_size; (void)ws_size;
    const float* latent = (const float*)d_in[0];
    const int*   ei     = (const int*)d_in[1];
    const float* Wd     = (const float*)d_in[2];
    const float* bd     = (const float*)d_in[3];
    const float* w1     = (const float*)d_in[4];
    const float* b1     = (const float*)d_in[5];
    const float* Wq     = (const float*)d_in[6];
    const float* bq     = (const float*)d_in[7];
    const float* Wk     = (const float*)d_in[8];
    const float* bk     = (const float*)d_in[9];
    const float* Wv     = (const float*)d_in[10];
    const float* gbias  = (const float*)d_in[11];
    const float* qw     = (const float*)d_in[12];
    const float* qb     = (const float*)d_in[13];
    float* out = (float*)d_out;

    float* ws     = (float*)d_ws;
    float* pdense = ws;                          // 131072
    float* Qg     = pdense + 64 * NND;           // 131072
    float* Kg     = Qg + BNN * EE;               // 131072
    float* Vg     = Kg + BNN * EE;               // 131072
    float* hg     = Vg + BNN * EE;               // 131072
    int*   hist   = (int*)(hg + BNN * EE);       // 16384
    int*   offs   = hist + BNN;                  // 16384
    int*   cnt    = offs + BNN;                  // 16384
    int*   ecol   = cnt + BNN;                   // 524288
    float* Mp     = (float*)(ecol + NEDGE);      // 80000
    float* BsT    = Mp + 80000;                  // 38400
    float* atT    = BsT + 38400;                 // 32768
    unsigned short* FvT = (unsigned short*)(atT + BSZ * LLH * LLH);  // 8*16384*64 bf16

    k_densep<<<dim3(64, 8), dim3(256), 0, stream>>>(latent, Wd, qw, qb, pdense, hist, BsT);
    k_gat<<<dim3(256), dim3(64), 0, stream>>>(pdense, bd, w1, b1, Wq, bq, Wk, bk, Wv,
                                              ei, Qg, Kg, Vg, hist);
    k_scan<<<dim3(1), dim3(1024), 0, stream>>>(hist, offs, cnt);
    k_scatter<<<dim3(NEDGE / 256), dim3(256), 0, stream>>>(ei, cnt, ecol);
    k_gatagg<<<dim3(BNN / 4), dim3(256), 0, stream>>>(ecol, offs, hist,
                                                      Qg, Kg, Vg, gbias, hg);
    k_convV<<<dim3(94, 8), dim3(256), 0, stream>>>(hg, qw, qb, FvT, Mp);
    k_Ssm<<<dim3(64, 8), dim3(256), 0, stream>>>(qw, qb, Mp, BsT, atT);
    k_attnV<<<dim3(256, 8), dim3(256), 0, stream>>>(FvT, atT, out);
}

// Round 16
// 134.837 us; speedup vs baseline: 1.1875x; 1.0165x over previous
//
#include <hip/hip_runtime.h>
#include <hip/hip_bf16.h>
#include <math.h>

#define BSZ 8
#define DDIM 512
#define NND 2048
#define EE 8
#define LLH 64
#define NEDGE 524288
#define BNN 16384          // BSZ*NND
#define OCC 1536           // 3*EE*LLH
#define DQ 16384           // per-third flat d dimension

typedef __attribute__((ext_vector_type(8))) short short8;
typedef __attribute__((ext_vector_type(4))) unsigned short ushort4v;

__device__ inline unsigned short f2bf(float x) {
    __hip_bfloat16 h = __float2bfloat16(x);
    return __builtin_bit_cast(unsigned short, h);
}
__device__ inline float bf2f(unsigned short u) {
    return __uint_as_float(((unsigned int)u) << 16);
}

// ---- 1. dense partials + zero hist + build BsT (by==1 slice) ----
__global__ __launch_bounds__(256) void k_densep(const float* __restrict__ latent,
                                                const float* __restrict__ Wd,
                                                const float* __restrict__ qw,
                                                const float* __restrict__ qb,
                                                float* __restrict__ pdense,
                                                int* __restrict__ hist,
                                                float* __restrict__ BsT) {
    int n0 = blockIdx.x * 32, d0 = blockIdx.y * 64;
    __shared__ float lat[8][64];
    int tid = threadIdx.x;
    if (blockIdx.y == 0) hist[blockIdx.x * 256 + tid] = 0;
    if (blockIdx.y == 1) {
        // BsT[jc*64+s] = B[j][s*24+sigma(c)], sigma(c)=c<16?c+8:c-16
        for (int idx = blockIdx.x * 256 + tid; idx < 38400; idx += 16384) {
            int jc = idx >> 6, s = idx & 63;
            int j = jc / 24, c = jc - j * 24;
            int sc = (c < 16) ? c + 8 : c - 16;
            BsT[idx] = (j < 24) ? qw[(size_t)j * OCC + s * 24 + sc] : qb[s * 24 + sc];
        }
    }
    #pragma unroll
    for (int r = 0; r < 2; ++r) {
        int i = r * 256 + tid;
        lat[i >> 6][i & 63] = latent[(i >> 6) * DDIM + d0 + (i & 63)];
    }
    __syncthreads();
    int nl = tid & 31, b = tid >> 5;
    const float* wp = Wd + (size_t)d0 * NND + n0 + nl;
    float acc = 0.f;
    #pragma unroll 8
    for (int d = 0; d < 64; ++d) acc += lat[b][d] * wp[(size_t)d * NND];
    pdense[((size_t)blockIdx.y * BSZ + b) * NND + n0 + nl] = acc;
}

// ---- 2. fused: reduce partials -> conv1 -> GAT QKV (one column per thread)
//         + edge hist (grid-stride). 512 blocks x 256 = 131072 threads ----
__global__ __launch_bounds__(256) void k_gat(const float* __restrict__ pdense,
                                             const float* __restrict__ bd,
                                             const float* __restrict__ w1,
                                             const float* __restrict__ b1,
                                             const float* __restrict__ Wq, const float* __restrict__ bq,
                                             const float* __restrict__ Wk, const float* __restrict__ bk,
                                             const float* __restrict__ Wv,
                                             const int* __restrict__ ei,
                                             float* __restrict__ Qg, float* __restrict__ Kg,
                                             float* __restrict__ Vg, int* __restrict__ hist) {
    int gid = blockIdx.x * 256 + threadIdx.x;   // 0..131071
    int i = gid >> 3, j = gid & 7;              // node-batch index, output column
    int b = i >> 11, n = i & (NND - 1);
    float sm = 0.f, s0 = 0.f, sp = 0.f;
    #pragma unroll
    for (int ds = 0; ds < 8; ++ds) {
        const float* p = pdense + ((size_t)ds * BSZ + b) * NND + n;
        if (n > 0) sm += p[-1];
        s0 += p[0];
        if (n < NND - 1) sp += p[1];
    }
    if (n > 0) sm += bd[n - 1];
    s0 += bd[n];
    if (n < NND - 1) sp += bd[n + 1];
    float q = bq[j], k = bk[j], v = 0.f;
    #pragma unroll
    for (int c = 0; c < EE; ++c) {
        float xc = sm * w1[c] + s0 * w1[EE + c] + sp * w1[2 * EE + c] + b1[c];
        q += xc * Wq[c * EE + j];
        k += xc * Wk[c * EE + j];
        v += xc * Wv[c * EE + j];
    }
    Qg[(size_t)i * EE + j] = (q >= 0.f) ? q : 0.2f * q;
    Kg[(size_t)i * EE + j] = (k >= 0.f) ? k : 0.2f * k;
    Vg[(size_t)i * EE + j] = v;
    // edge histogram: 4 coalesced grid-stride atomics per thread
    #pragma unroll
    for (int r = 0; r < 4; ++r)
        atomicAdd(hist + ei[gid + r * 131072], 1);
}

// ---- 3. exclusive prefix sum over 16384 counts ----
__global__ __launch_bounds__(1024) void k_scan(const int* __restrict__ hist,
                                               int* __restrict__ offs,
                                               int* __restrict__ cnt) {
    int tid = threadIdx.x;
    int lane = tid & 63, wv = tid >> 6;
    const int4* hp = (const int4*)(hist + tid * 16);
    int4 a = hp[0], b4 = hp[1], c4 = hp[2], d4 = hp[3];
    int h[16] = {a.x, a.y, a.z, a.w, b4.x, b4.y, b4.z, b4.w,
                 c4.x, c4.y, c4.z, c4.w, d4.x, d4.y, d4.z, d4.w};
    int mysum = 0;
    #pragma unroll
    for (int i = 0; i < 16; ++i) mysum += h[i];
    int inc = mysum;
    #pragma unroll
    for (int off = 1; off < 64; off <<= 1) {
        int u = __shfl_up(inc, off, 64);
        if (lane >= off) inc += u;
    }
    __shared__ int wtot[16];
    if (lane == 63) wtot[wv] = inc;
    __syncthreads();
    if (tid < 16) {
        int t = wtot[tid];
        #pragma unroll
        for (int off = 1; off < 16; off <<= 1) {
            int u = __shfl_up(t, off, 16);
            if (tid >= off) t += u;
        }
        wtot[tid] = t;
    }
    __syncthreads();
    int run = (wv ? wtot[wv - 1] : 0) + inc - mysum;
    #pragma unroll
    for (int i = 0; i < 16; ++i) {
        offs[tid * 16 + i] = run;
        cnt[tid * 16 + i] = run;
        run += h[i];
    }
}

// ---- 4. scatter edge columns into destination buckets ----
__global__ void k_scatter(const int* __restrict__ ei, int* __restrict__ cnt,
                          int* __restrict__ ecol) {
    int e = blockIdx.x * 256 + threadIdx.x;
    if (e >= NEDGE) return;
    int r = ei[e], c = ei[NEDGE + e];
    int pos = atomicAdd(cnt + r, 1);
    ecol[pos] = c;
}

// ---- 5. per-row gather + online softmax + aggregate ----
__global__ __launch_bounds__(256) void k_gatagg(const int* __restrict__ ecol,
                                                const int* __restrict__ offs,
                                                const int* __restrict__ hist,
                                                const float* __restrict__ Qg,
                                                const float* __restrict__ Kg,
                                                const float* __restrict__ Vg,
                                                const float* __restrict__ gbias,
                                                float* __restrict__ hg) {
    int row = __builtin_amdgcn_readfirstlane(blockIdx.x * 4 + (threadIdx.x >> 6));
    int lane = threadIdx.x & 63;
    const float* Qr = Qg + (size_t)row * EE;
    float q0 = Qr[0], q1 = Qr[1], q2 = Qr[2], q3 = Qr[3];
    float q4 = Qr[4], q5 = Qr[5], q6 = Qr[6], q7 = Qr[7];
    int beg = offs[row], deg = hist[row];
    int total = deg + 1;
    float m = -INFINITY, l = 0.f;
    float acc[EE];
    #pragma unroll
    for (int j = 0; j < EE; ++j) acc[j] = 0.f;
    for (int base = 0; base < total; base += 64) {
        int idx = base + lane;
        int c = row;
        if (idx < deg) c = ecol[beg + idx];
        const float4* K4 = (const float4*)(Kg + (size_t)c * EE);
        float4 ka = K4[0], kb = K4[1];
        float s = q0*ka.x + q1*ka.y + q2*ka.z + q3*ka.w
                + q4*kb.x + q5*kb.y + q6*kb.z + q7*kb.w;
        if (idx >= total) s = -INFINITY;
        float pm = s;
        #pragma unroll
        for (int off = 32; off > 0; off >>= 1) pm = fmaxf(pm, __shfl_xor(pm, off));
        float nm = fmaxf(m, pm);
        float scale = __expf(m - nm);
        float p = (idx < total) ? __expf(s - nm) : 0.f;
        float ps = p;
        #pragma unroll
        for (int off = 32; off > 0; off >>= 1) ps += __shfl_xor(ps, off);
        l = l * scale + ps;
        const float4* V4 = (const float4*)(Vg + (size_t)c * EE);
        float4 va = V4[0], vb = V4[1];
        float pv[EE] = {p*va.x, p*va.y, p*va.z, p*va.w, p*vb.x, p*vb.y, p*vb.z, p*vb.w};
        #pragma unroll
        for (int j = 0; j < EE; ++j) {
            float t = pv[j];
            #pragma unroll
            for (int off = 32; off > 0; off >>= 1) t += __shfl_xor(t, off);
            acc[j] = acc[j] * scale + t;
        }
        m = nm;
    }
    if (lane < EE)
        hg[(size_t)row * EE + lane] = acc[lane] / l + gbias[lane];
}

// ---- 6. v-conv (8-node chunks) -> FvT[b][d][s]  ||  Mpart (bx>=86) ----
__global__ __launch_bounds__(256) void k_convV(const float* __restrict__ hg,
                                               const float* __restrict__ qw,
                                               const float* __restrict__ qb,
                                               unsigned short* __restrict__ FvT,
                                               float* __restrict__ Mpart) {
    int bx = blockIdx.x, b = blockIdx.y, tid = threadIdx.x;
    if (bx < 86) {
        int n0 = 682 + bx * 8;
        __shared__ float hs[10 * EE];
        __shared__ unsigned short st[8 * 768];
        for (int i = tid; i < 10 * EE; i += 256) {
            int nn = n0 - 1 + (i >> 3);
            hs[i] = (nn < NND) ? hg[((size_t)b * NND + nn) * EE + (i & 7)] : 0.f;
        }
        __syncthreads();
        int dbase = n0 * 24 - DQ;
        #pragma unroll
        for (int pass = 0; pass < 2; ++pass) {
            if (pass) __syncthreads();
            float w[3][24], bias[3];
            #pragma unroll
            for (int rr = 0; rr < 3; ++rr) {
                int o = pass * 768 + rr * 256 + tid;
                bias[rr] = qb[o];
                #pragma unroll
                for (int kk = 0; kk < 24; ++kk) w[rr][kk] = qw[kk * OCC + o];
            }
            #pragma unroll
            for (int nn = 0; nn < 8; ++nn) {
                const float* hv = &hs[nn * EE];
                float a0 = bias[0], a1 = bias[1], a2 = bias[2];
                #pragma unroll
                for (int kk = 0; kk < 24; ++kk) {
                    float h = hv[kk];
                    a0 += h * w[0][kk]; a1 += h * w[1][kk]; a2 += h * w[2][kk];
                }
                st[nn * 768 + tid]       = f2bf(a0);
                st[nn * 768 + tid + 256] = f2bf(a1);
                st[nn * 768 + tid + 512] = f2bf(a2);
            }
            __syncthreads();
            int l0 = pass * 32;
            #pragma unroll
            for (int it = 0; it < 6; ++it) {
                int idx = it * 256 + tid;
                int dl = idx >> 3, s4 = idx & 7;
                int d = dbase + dl;
                if (d < 0 || d >= DQ) continue;
                int nn = dl / 24, c = dl - nn * 24;
                const unsigned short* sb = st + nn * 768 + c;
                ushort4v v4 = { sb[(s4 * 4 + 0) * 24], sb[(s4 * 4 + 1) * 24],
                                sb[(s4 * 4 + 2) * 24], sb[(s4 * 4 + 3) * 24] };
                *(ushort4v*)(FvT + ((size_t)b * DQ + d) * 64 + l0 + s4 * 4) = v4;
            }
        }
    } else {
        int sp = bx - 86;
        int nq0 = sp * 86;
        __shared__ float hq[88 * EE];
        __shared__ float hk[90 * EE];
        for (int i = tid; i < 88 * EE; i += 256) {
            int r = nq0 - 1 + (i >> 3);
            hq[i] = (r >= 0 && r < NND) ? hg[((size_t)b * NND + r) * EE + (i & 7)] : 0.f;
        }
        for (int i = tid; i < 90 * EE; i += 256) {
            int r = nq0 + 1364 + (i >> 3);
            hk[i] = (r < NND) ? hg[((size_t)b * NND + r) * EE + (i & 7)] : 0.f;
        }
        __syncthreads();
        int cnt1 = 683 - nq0; if (cnt1 > 86) cnt1 = 86; if (cnt1 < 0) cnt1 = 0;
        int cnt2 = 682 - nq0; if (cnt2 > 86) cnt2 = 86; if (cnt2 < 0) cnt2 = 0;
        for (int idx = tid; idx < 1250; idx += 256) {
            int mm = idx / 625, p = idx - (idx / 625) * 625;
            int i = p / 25, j = p - (p / 25) * 25;
            int cnt = mm ? cnt2 : cnt1;
            int qi = i >> 3, qe = i & 7;
            int kj = (j >> 3) + mm, ke = j & 7;
            float acc = 0.f;
            if (i < 24 && j < 24) {
                for (int nl = 0; nl < cnt; ++nl)
                    acc += hq[(nl + qi) * EE + qe] * hk[(nl + kj) * EE + ke];
            } else if (i < 24) {
                for (int nl = 0; nl < cnt; ++nl) acc += hq[(nl + qi) * EE + qe];
            } else if (j < 24) {
                for (int nl = 0; nl < cnt; ++nl) acc += hk[(nl + kj) * EE + ke];
            } else {
                acc = (float)cnt;
            }
            Mpart[((size_t)(sp * 8 + b)) * 1250 + idx] = acc;
        }
    }
}

// ---- 7. S contraction + softmax, grid (64 t, 8 b) x 256 thr ----
__global__ __launch_bounds__(256) void k_Ssm(const float* __restrict__ qw,
                                             const float* __restrict__ qb,
                                             const float* __restrict__ Mpart,
                                             const float* __restrict__ BsT,
                                             float* __restrict__ atT) {
    int t = blockIdx.x, b = blockIdx.y, tid = threadIdx.x;
    __shared__ float Ms[1250];
    __shared__ float As[600];
    __shared__ float T1[600];
    __shared__ float part[4][64];
    for (int idx = tid; idx < 1250; idx += 256) {
        float s = 0.f;
        #pragma unroll
        for (int sp = 0; sp < 8; ++sp)
            s += Mpart[((size_t)(sp * 8 + b)) * 1250 + idx];
        Ms[idx] = s;
    }
    for (int idx = tid; idx < 600; idx += 256) {
        int i = idx / 24, c = idx - (idx / 24) * 24;
        As[idx] = (i < 24) ? qw[(size_t)i * OCC + t * 24 + c] : qb[t * 24 + c];
    }
    __syncthreads();
    for (int idx = tid; idx < 600; idx += 256) {
        int j = idx / 24, c = idx - (idx / 24) * 24;
        int mo = (c < 16) ? 0 : 625;
        float acc = 0.f;
        #pragma unroll 5
        for (int i = 0; i < 25; ++i)
            acc += Ms[mo + i * 25 + j] * As[i * 24 + c];
        T1[idx] = acc;
    }
    __syncthreads();
    int s = tid & 63, g = tid >> 6;
    float acc = 0.f;
    const float* bp = BsT + (size_t)(g * 150) * 64 + s;
    #pragma unroll 10
    for (int u = 0; u < 150; ++u)
        acc += T1[g * 150 + u] * bp[(size_t)u * 64];
    part[g][s] = acc;
    __syncthreads();
    if (tid < 64) {
        float v = part[0][s] + part[1][s] + part[2][s] + part[3][s];
        float m = v;
        #pragma unroll
        for (int off = 32; off > 0; off >>= 1) m = fmaxf(m, __shfl_xor(m, off));
        float e = __expf(v - m);
        float sum = e;
        #pragma unroll
        for (int off = 32; off > 0; off >>= 1) sum += __shfl_xor(sum, off);
        atT[((size_t)b * LLH + s) * LLH + t] = e / sum;
    }
}

// ---- 8. out[b][t][d] = sum_s atT[b][s][t] * v[s][d]; FvT coalesced staging ----
__global__ __launch_bounds__(256) void k_attnV(const unsigned short* __restrict__ FvT,
                                               const float* __restrict__ atT,
                                               float* __restrict__ out) {
    int b = blockIdx.y;
    int d0 = blockIdx.x * 64;
    int tid = threadIdx.x;
    __shared__ float vtf[64][65];
    #pragma unroll
    for (int r = 0; r < 2; ++r) {
        int idx = r * 256 + tid;
        int dl = idx >> 3, g = idx & 7;
        short8 v = *(const short8*)(FvT + ((size_t)b * DQ + d0 + dl) * 64 + g * 8);
        #pragma unroll
        for (int j = 0; j < 8; ++j)
            vtf[dl][g * 8 + j] = bf2f((unsigned short)v[j]);
    }
    __syncthreads();
    int lane = tid & 63;
    int t0 = __builtin_amdgcn_readfirstlane((tid >> 6) * 16);
    const float* arow = atT + (size_t)b * LLH * LLH + t0;
    float acc[16];
    #pragma unroll
    for (int tt = 0; tt < 16; ++tt) acc[tt] = 0.f;
    #pragma unroll 4
    for (int s = 0; s < LLH; ++s) {
        float vv = vtf[lane][s];
        #pragma unroll
        for (int tt = 0; tt < 16; ++tt)
            acc[tt] += arow[s * LLH + tt] * vv;
    }
    float* ob = out + ((size_t)b * LLH + t0) * DQ + d0 + lane;
    #pragma unroll
    for (int tt = 0; tt < 16; ++tt) ob[(size_t)tt * DQ] = acc[tt];
}

extern "C" void kernel_launch(void* const* d_in, const int* in_sizes, int n_in,
                              void* d_out, int out_size, void* d_ws, size_t ws_size,
                              hipStream_t stream) {
    (void)in_sizes; (void)n_in; (void)out_size; (void)ws_size;
    const float* latent = (const float*)d_in[0];
    const int*   ei     = (const int*)d_in[1];
    const float* Wd     = (const float*)d_in[2];
    const float* bd     = (const float*)d_in[3];
    const float* w1     = (const float*)d_in[4];
    const float* b1     = (const float*)d_in[5];
    const float* Wq     = (const float*)d_in[6];
    const float* bq     = (const float*)d_in[7];
    const float* Wk     = (const float*)d_in[8];
    const float* bk     = (const float*)d_in[9];
    const float* Wv     = (const float*)d_in[10];
    const float* gbias  = (const float*)d_in[11];
    const float* qw     = (const float*)d_in[12];
    const float* qb     = (const float*)d_in[13];
    float* out = (float*)d_out;

    float* ws     = (float*)d_ws;
    float* pdense = ws;                          // 131072
    float* Qg     = pdense + 64 * NND;           // 131072
    float* Kg     = Qg + BNN * EE;               // 131072
    float* Vg     = Kg + BNN * EE;               // 131072
    float* hg     = Vg + BNN * EE;               // 131072
    int*   hist   = (int*)(hg + BNN * EE);       // 16384
    int*   offs   = hist + BNN;                  // 16384
    int*   cnt    = offs + BNN;                  // 16384
    int*   ecol   = cnt + BNN;                   // 524288
    float* Mp     = (float*)(ecol + NEDGE);      // 80000
    float* BsT    = Mp + 80000;                  // 38400
    float* atT    = BsT + 38400;                 // 32768
    unsigned short* FvT = (unsigned short*)(atT + BSZ * LLH * LLH);  // 8*16384*64 bf16

    k_densep<<<dim3(64, 8), dim3(256), 0, stream>>>(latent, Wd, qw, qb, pdense, hist, BsT);
    k_gat<<<dim3(512), dim3(256), 0, stream>>>(pdense, bd, w1, b1, Wq, bq, Wk, bk, Wv,
                                               ei, Qg, Kg, Vg, hist);
    k_scan<<<dim3(1), dim3(1024), 0, stream>>>(hist, offs, cnt);
    k_scatter<<<dim3(NEDGE / 256), dim3(256), 0, stream>>>(ei, cnt, ecol);
    k_gatagg<<<dim3(BNN / 4), dim3(256), 0, stream>>>(ecol, offs, hist,
                                                      Qg, Kg, Vg, gbias, hg);
    k_convV<<<dim3(94, 8), dim3(256), 0, stream>>>(hg, qw, qb, FvT, Mp);
    k_Ssm<<<dim3(64, 8), dim3(256), 0, stream>>>(qw, qb, Mp, BsT, atT);
    k_attnV<<<dim3(256, 8), dim3(256), 0, stream>>>(FvT, atT, out);
}